// Round 9
// baseline (149.752 us; speedup 1.0000x reference)
//
#include <hip/hip_runtime.h>
#include <math.h>

#define PI_F 3.14159265358979323846f
#define BB 2
#define LL 1024
#define NCH 64
#define CHUNK 32
#define NCHUNK (LL/CHUNK)
#define NW 1408          // Wb rows: 512 Wv | 256 Wg1 | 16 Wk | 16 Wq | 96 pad0 | 512 Wo'

typedef __attribute__((ext_vector_type(8))) short short8;
typedef __attribute__((ext_vector_type(4))) float floatx4;
typedef const __attribute__((address_space(1))) unsigned int cgu32;
typedef __attribute__((address_space(3))) unsigned int lu32;

__device__ __forceinline__ unsigned short f2bf(float f){
    unsigned u = __float_as_uint(f);
    unsigned r = (u + 0x7fff + ((u >> 16) & 1)) >> 16;   // RNE
    return (unsigned short)r;
}

// ---- prep: weights -> bf16 Wb[n][k] (Wo rows pre-scaled by ln_g), bcat,
//      G/B LN-fold vectors, zero stats, x -> bf16 xb ----
__global__ __launch_bounds__(128) void k_prep(
    const float* __restrict__ Wv, const float* __restrict__ Wg1,
    const float* __restrict__ Wk, const float* __restrict__ Wq,
    const float* __restrict__ Wo,
    const float* __restrict__ bv, const float* __restrict__ bg1,
    const float* __restrict__ bk, const float* __restrict__ bq,
    const float* __restrict__ bo, const float* __restrict__ x,
    const float* __restrict__ ln_g, const float* __restrict__ ln_b,
    unsigned short* __restrict__ Wb, float* __restrict__ bcat,
    float* __restrict__ Gv, float* __restrict__ Bv, float* __restrict__ stats,
    unsigned short* __restrict__ xb)
{
    const int bid = blockIdx.x, tid = threadIdx.x;
    if (bid < NW){
        if (bid < 32) stats[bid*128 + tid] = 0.f;         // zero LN-stats buffer
        const int n = bid;
        const float* src = (n<512) ? Wv  + (size_t)n*512
                         : (n<768) ? Wg1 + (size_t)(n-512)*512
                         : (n<784) ? Wk  + (size_t)(n-768)*512
                         : (n<800) ? Wq  + (size_t)(n-784)*512
                         : (n<896) ? (const float*)0
                                   : Wo  + (size_t)(n-896)*512;
        float4 v = make_float4(0.f,0.f,0.f,0.f);
        if (src) v = ((const float4*)src)[tid];
        if (n >= 896){
            // Wo row: emit Wo' = Wo*ln_g (bf16) and reduce G = sum g*W, B = sum b*W
            float4 g4 = ((const float4*)ln_g)[tid];
            float4 b4 = ((const float4*)ln_b)[tid];
            ushort4 o;
            o.x=f2bf(v.x*g4.x); o.y=f2bf(v.y*g4.y);
            o.z=f2bf(v.z*g4.z); o.w=f2bf(v.w*g4.w);
            ((ushort4*)(Wb + (size_t)n*512))[tid] = o;
            float pg = v.x*g4.x + v.y*g4.y + v.z*g4.z + v.w*g4.w;
            float pb = v.x*b4.x + v.y*b4.y + v.z*b4.z + v.w*b4.w;
            #pragma unroll
            for (int off=32; off; off>>=1){
                pg += __shfl_xor(pg, off, 64); pb += __shfl_xor(pb, off, 64);
            }
            __shared__ float red[4];
            const int wv = tid >> 6;
            if ((tid & 63) == 0){ red[wv*2] = pg; red[wv*2+1] = pb; }
            __syncthreads();
            if (tid == 0){
                Gv[n-896] = red[0] + red[2];
                Bv[n-896] = red[1] + red[3] + bo[n-896];
            }
        } else {
            ushort4 o; o.x=f2bf(v.x); o.y=f2bf(v.y); o.z=f2bf(v.z); o.w=f2bf(v.w);
            ((ushort4*)(Wb + (size_t)n*512))[tid] = o;
        }
        if (tid == 0)
            bcat[n] = (n<512)?bv[n] : (n<768)?bg1[n-512] : (n<784)?bk[n-768]
                    : (n<800)?bq[n-784] : 0.f;
    } else {
        const size_t i = (size_t)(bid - NW)*128 + tid;    // float4 index
        float4 v = ((const float4*)x)[i];
        ushort4 o; o.x=f2bf(v.x); o.y=f2bf(v.y); o.z=f2bf(v.z); o.w=f2bf(v.w);
        ((ushort4*)xb)[i] = o;
    }
}

// ---- MFMA 64x64x512 tile core (verified rounds 3-8) ----
__device__ __forceinline__ void gemm64x64(
    const unsigned short* Ag, const unsigned short* Bg,
    short* As, short* Bs, int tid, floatx4 acc[2][2])
{
    const int lane = tid & 63, w = tid >> 6;
    const int wm = w & 1, wn = w >> 1;
    const int q = lane >> 4, m15 = lane & 15;
    for (int kt = 0; kt < 512; kt += 64) {
        __syncthreads();
        #pragma unroll
        for (int i = 0; i < 2; ++i) {
            const int rowbase = (w*2 + i) * 8;
            const int r  = rowbase + (lane >> 3);
            const int gb = (lane & 7) ^ (r & 7);
            __builtin_amdgcn_global_load_lds(
                (cgu32*)(const void*)(Ag + (size_t)r*512 + kt + gb*8),
                (lu32*)(As + rowbase*64), 16, 0, 0);
            __builtin_amdgcn_global_load_lds(
                (cgu32*)(const void*)(Bg + (size_t)r*512 + kt + gb*8),
                (lu32*)(Bs + rowbase*64), 16, 0, 0);
        }
        __syncthreads();
        #pragma unroll
        for (int k32 = 0; k32 < 64; k32 += 32) {
            short8 af[2], bf[2];
            #pragma unroll
            for (int t = 0; t < 2; ++t) {
                const int ra  = 32*wm + 16*t + m15;
                const int sba = ((k32>>3) + q) ^ (ra & 7);
                af[t] = *(const short8*)(As + ra*64 + sba*8);
                const int rb  = 32*wn + 16*t + m15;
                const int sbb = ((k32>>3) + q) ^ (rb & 7);
                bf[t] = *(const short8*)(Bs + rb*64 + sbb*8);
            }
            #pragma unroll
            for (int mt = 0; mt < 2; ++mt)
                #pragma unroll
                for (int nt = 0; nt < 2; ++nt)
                    acc[mt][nt] = __builtin_amdgcn_mfma_f32_16x16x32_bf16(
                        af[mt], bf[nt], acc[mt][nt], 0, 0, 0);
        }
    }
}

// ---- kg1f: fused GEMM1.
//  blocks 0..31  : act 64x288 tiles (scheduled FIRST — longest pole)
//  blocks 32..287: Vr 64x64 tiles -> Vt bf16 [b][d][l]
__global__ __launch_bounds__(256,2) void kg1f(
    const unsigned short* __restrict__ xb, const unsigned short* __restrict__ Wb,
    const float* __restrict__ bcat, const float* __restrict__ Wg2,
    const float* __restrict__ bg2, const float* __restrict__ set_w,
    const float* __restrict__ pos_phases, const float* __restrict__ pos_weight,
    unsigned short* __restrict__ Vt,
    unsigned short* __restrict__ ab, unsigned short* __restrict__ Rb,
    unsigned short* __restrict__ aT)
{
    __shared__ short smem[22528];       // 44 KB union (act path); Vr path uses 16 KB
    const int bid = blockIdx.x, tid = threadIdx.x;
    const int lane = tid & 63, w = tid >> 6;
    const int q = lane >> 4, m15 = lane & 15;

    if (bid >= 32){
        // ---------------- Vr path: 64x64 tiles (verified) ----------
        short* As = smem;               // 64*64
        short* Bs = smem + 64*64;
        const int vb = bid - 32;
        const int row0 = (vb >> 3)*64, n0 = (vb & 7)*64;
        floatx4 acc[2][2];
        #pragma unroll
        for (int mt=0;mt<2;++mt)
            #pragma unroll
            for (int nt=0;nt<2;++nt) acc[mt][nt] = (floatx4){0.f,0.f,0.f,0.f};
        gemm64x64(xb + (size_t)row0*512, Wb + (size_t)n0*512, As, Bs, tid, acc);
        const int wm = w & 1, wn = w >> 1;
        const int b = row0 >> 10, lb = row0 & 1023;
        #pragma unroll
        for (int mt=0;mt<2;++mt)
            #pragma unroll
            for (int nt=0;nt<2;++nt){
                const int d = n0 + 32*wn + 16*nt + m15;
                const float bb = bcat[d];
                const int l0 = lb + 32*wm + 16*mt + q*4;
                ushort4 o;
                o.x = f2bf(acc[mt][nt][0] + bb);
                o.y = f2bf(acc[mt][nt][1] + bb);
                o.z = f2bf(acc[mt][nt][2] + bb);
                o.w = f2bf(acc[mt][nt][3] + bb);
                *(ushort4*)(Vt + ((size_t)(b*512 + d))*1024 + l0) = o;
            }
    } else {
        // ---------------- act path: 64 rows x 288 cols (verified round 7) ----
        short* As2 = smem;              // 64*64  (8 KB)
        short* Bs2 = smem + 64*64;      // 288*64 (36 KB)
        const int r0 = bid*64;
        floatx4 acc2[18];
        #pragma unroll
        for (int nt=0;nt<18;++nt) acc2[nt] = (floatx4){0.f,0.f,0.f,0.f};
        for (int kt = 0; kt < 512; kt += 64){
            __syncthreads();
            #pragma unroll
            for (int i=0;i<2;++i){
                const int rowbase = (w*2 + i)*8;
                const int r = rowbase + (lane >> 3);
                const int gb = (lane & 7) ^ (r & 7);
                __builtin_amdgcn_global_load_lds(
                    (cgu32*)(const void*)(xb + (size_t)(r0 + r)*512 + kt + gb*8),
                    (lu32*)(As2 + rowbase*64), 16, 0, 0);
            }
            #pragma unroll
            for (int i=0;i<9;++i){
                const int rowbase = (w*9 + i)*8;
                const int r = rowbase + (lane >> 3);
                const int gb = (lane & 7) ^ (r & 7);
                __builtin_amdgcn_global_load_lds(
                    (cgu32*)(const void*)(Wb + (size_t)(512 + r)*512 + kt + gb*8),
                    (lu32*)(Bs2 + rowbase*64), 16, 0, 0);
            }
            __syncthreads();
            #pragma unroll
            for (int k32 = 0; k32 < 64; k32 += 32){
                const int ra  = 16*w + m15;
                const int sba = ((k32>>3) + q) ^ (ra & 7);
                short8 af = *(const short8*)(As2 + ra*64 + sba*8);
                #pragma unroll
                for (int nt=0;nt<18;++nt){
                    const int rb  = 16*nt + m15;
                    const int sbb = ((k32>>3) + q) ^ (rb & 7);
                    short8 bf = *(const short8*)(Bs2 + rb*64 + sbb*8);
                    acc2[nt] = __builtin_amdgcn_mfma_f32_16x16x32_bf16(
                        af, bf, acc2[nt], 0, 0, 0);
                }
            }
        }
        // ---- epilogue: gate + phases for rows r0+16w .. +15 ----
        float s0=set_w[0], s1=set_w[1], s2=set_w[2], s3=set_w[3];
        float mx = fmaxf(fmaxf(s0,s1), fmaxf(s2,s3));
        float e0=expf(s0-mx), e1=expf(s1-mx), e2=expf(s2-mx), e3=expf(s3-mx);
        float esum = e0+e1+e2+e3;
        float spw = 1.f/(1.f+expf(-pos_weight[0]));
        float b2 = bg2[0];
        float part[4] = {0.f,0.f,0.f,0.f};
        #pragma unroll
        for (int nt=0;nt<16;++nt){
            const float w2 = Wg2[16*nt + m15];
            const float hb = bcat[512 + 16*nt + m15];
            #pragma unroll
            for (int reg=0;reg<4;++reg){
                float hv = acc2[nt][reg] + hb;
                float ge = 0.5f*hv*(1.f + erff(hv*0.70710678118f));
                part[reg] += ge*w2;
            }
        }
        #pragma unroll
        for (int off=8; off; off>>=1)
            #pragma unroll
            for (int reg=0;reg<4;++reg) part[reg] += __shfl_xor(part[reg], off, 64);
        const int j = m15;
        const float bkj = bcat[768 + j], bqj = bcat[784 + j];
        const float wsm = (j<4?e0: j<8?e1: j<12?e2: e3) / esum;
        #pragma unroll
        for (int reg=0;reg<4;++reg){
            const int row = r0 + 16*w + q*4 + reg;
            const int l = row & (LL-1), b = row >> 10;
            float g = 1.f/(1.f+expf(-(part[reg] + b2)));
            float kang = PI_F*tanhf(acc2[16][reg] + bkj);
            float qang = PI_F*tanhf(acc2[17][reg] + bqj);
            float rnorm = 1.f/(2.f*sqrtf((float)(l+1)));
            float av[4], rv[4];
            av[0] = cosf(kang); av[1] = sinf(kang);
            float cw = g*wsm*rnorm;
            rv[0] = cw*cosf(qang); rv[1] = cw*sinf(qang);
            float ph = pos_phases[(size_t)l*16 + j];
            float pc = cosf(ph), ps = sinf(ph);
            av[2] = pc; av[3] = ps;
            float cp = (1.f-g)*spw*rnorm;
            rv[2] = cp*pc; rv[3] = cp*ps;
            unsigned short* arow = ab + (size_t)row*NCH;
            unsigned short* Rrow = Rb + (size_t)row*NCH;
            #pragma unroll
            for (int t=0;t<4;++t){
                arow[16*t + j] = f2bf(av[t]);
                Rrow[16*t + j] = f2bf(rv[t]);
                aT[((size_t)(b*NCH + 16*t + j))*1024 + l] = f2bf(av[t]);
            }
        }
    }
}

// ---- K2a (MFMA): P[b][c][d][k], z-split x4 (256 blocks) ----
__global__ __launch_bounds__(256) void k2a_chunksum(
    const unsigned short* __restrict__ aT, const unsigned short* __restrict__ Vt,
    float* __restrict__ P)
{
    const int c = blockIdx.x, b = blockIdx.y, z = blockIdx.z;
    const int tid = threadIdx.x, lane = tid & 63, w = tid >> 6;
    const int q = lane >> 4, m15 = lane & 15;
    short8 af[4];
    #pragma unroll
    for (int mt=0;mt<4;++mt)
        af[mt] = *(const short8*)(aT + ((size_t)b*NCH + 16*mt + m15)*1024 + c*32 + q*8);
    floatx4 acc[4][2];
    #pragma unroll
    for (int mt=0;mt<4;++mt)
        #pragma unroll
        for (int nt=0;nt<2;++nt) acc[mt][nt] = (floatx4){0.f,0.f,0.f,0.f};
    #pragma unroll
    for (int nt=0;nt<2;++nt){
        const int d = z*128 + w*32 + 16*nt + m15;
        short8 bf = *(const short8*)(Vt + ((size_t)(b*512 + d))*1024 + c*32 + q*8);
        #pragma unroll
        for (int mt=0;mt<4;++mt)
            acc[mt][nt] = __builtin_amdgcn_mfma_f32_16x16x32_bf16(af[mt], bf, acc[mt][nt], 0,0,0);
    }
    float* Pc = P + ((size_t)(b*NCHUNK + c))*512*NCH;
    #pragma unroll
    for (int mt=0;mt<4;++mt)
        #pragma unroll
        for (int nt=0;nt<2;++nt){
            const int d = z*128 + w*32 + 16*nt + m15;
            *(floatx4*)(Pc + (size_t)d*NCH + 16*mt + q*4) = acc[mt][nt];
        }
}

// ---- K2b: exclusive prefix over chunks -> S0t bf16 (loads fully unrolled) ----
__global__ __launch_bounds__(256) void k2b_prefix(
    const float* __restrict__ P, unsigned short* __restrict__ S0t)
{
    const int b = blockIdx.y;
    const size_t idx = (size_t)blockIdx.x*256 + threadIdx.x;   // over 512*64
    const size_t base = (size_t)b*NCHUNK*512*NCH + idx;
    float vcs[NCHUNK];
    #pragma unroll
    for (int c=0;c<NCHUNK;++c)
        vcs[c] = P[base + (size_t)c*512*NCH];      // 32 independent loads in flight
    float run = 0.f;
    #pragma unroll
    for (int c=0;c<NCHUNK;++c){
        S0t[base + (size_t)c*512*NCH] = f2bf(run);
        run += vcs[c];
    }
}

// ---- K2c (MFMA): T_raw = tril(R a^T)@V + R@S0, d-sliced x4, barrier-free.
// Each wave computes M into a wave-private Msh (same-wave LDS RAW: lgkmcnt
// only — verified round 6). Emits raw Tn bf16 + atomic per-row LN partials.
__global__ __launch_bounds__(256) void k2c_scan(
    const unsigned short* __restrict__ ab, const unsigned short* __restrict__ Rb,
    const unsigned short* __restrict__ Vt, const unsigned short* __restrict__ S0t,
    unsigned short* __restrict__ Tn, float* __restrict__ stats)
{
    __shared__ short Msh[4][32*32];
    const int c = blockIdx.x, b = blockIdx.y, z = blockIdx.z;
    const int tid = threadIdx.x, lane = tid & 63, w = tid >> 6;
    const int q = lane >> 4, m15 = lane & 15;
    const int grow = b*1024 + c*32;

    // M = tril(R @ a^T), per wave
    short8 ra[2][2], av[2][2];
    #pragma unroll
    for (int ks=0;ks<2;++ks)
        #pragma unroll
        for (int t=0;t<2;++t){
            ra[ks][t] = *(const short8*)(Rb + (size_t)(grow + 16*t + m15)*NCH + ks*32 + q*8);
            av[ks][t] = *(const short8*)(ab + (size_t)(grow + 16*t + m15)*NCH + ks*32 + q*8);
        }
    floatx4 mcc[2][2];
    #pragma unroll
    for (int mt=0;mt<2;++mt)
        #pragma unroll
        for (int nt=0;nt<2;++nt) mcc[mt][nt] = (floatx4){0.f,0.f,0.f,0.f};
    #pragma unroll
    for (int ks=0;ks<2;++ks)
        #pragma unroll
        for (int mt=0;mt<2;++mt)
            #pragma unroll
            for (int nt=0;nt<2;++nt)
                mcc[mt][nt] = __builtin_amdgcn_mfma_f32_16x16x32_bf16(
                    ra[ks][mt], av[ks][nt], mcc[mt][nt], 0,0,0);
    short* Mw = &Msh[w][0];
    #pragma unroll
    for (int mt=0;mt<2;++mt)
        #pragma unroll
        for (int nt=0;nt<2;++nt){
            const int nl = 16*nt + m15;
            #pragma unroll
            for (int reg=0;reg<4;++reg){
                const int ml = 16*mt + q*4 + reg;
                Mw[ml*32 + nl] = (nl <= ml) ? (short)f2bf(mcc[mt][nt][reg]) : (short)0;
            }
        }
    short8 a1[2];
    #pragma unroll
    for (int mt=0;mt<2;++mt)
        a1[mt] = *(const short8*)(Mw + (16*mt + m15)*32 + q*8);

    // T = M@V + R@S0 over this wave's 32-col d-slice
    floatx4 acc[2][2];
    #pragma unroll
    for (int mt=0;mt<2;++mt)
        #pragma unroll
        for (int nt=0;nt<2;++nt) acc[mt][nt] = (floatx4){0.f,0.f,0.f,0.f};
    const unsigned short* S0c = S0t + ((size_t)(b*NCHUNK + c))*512*NCH;
    #pragma unroll
    for (int nt=0;nt<2;++nt){
        const int d = z*128 + w*32 + 16*nt + m15;
        short8 vfr = *(const short8*)(Vt + ((size_t)(b*512 + d))*1024 + c*32 + q*8);
        #pragma unroll
        for (int mt=0;mt<2;++mt)
            acc[mt][nt] = __builtin_amdgcn_mfma_f32_16x16x32_bf16(a1[mt], vfr, acc[mt][nt], 0,0,0);
        #pragma unroll
        for (int ks=0;ks<2;++ks){
            short8 sfr = *(const short8*)(S0c + (size_t)d*NCH + ks*32 + q*8);
            #pragma unroll
            for (int mt=0;mt<2;++mt)
                acc[mt][nt] = __builtin_amdgcn_mfma_f32_16x16x32_bf16(ra[ks][mt], sfr, acc[mt][nt], 0,0,0);
        }
    }
    // write raw Tn + per-row LN partial sums
    #pragma unroll
    for (int mt=0;mt<2;++mt){
        float s[4] = {0.f,0.f,0.f,0.f}, sq[4] = {0.f,0.f,0.f,0.f};
        #pragma unroll
        for (int nt=0;nt<2;++nt){
            const int d = z*128 + w*32 + 16*nt + m15;
            #pragma unroll
            for (int reg=0;reg<4;++reg){
                const float vv = acc[mt][nt][reg];
                Tn[(size_t)(grow + 16*mt + q*4 + reg)*512 + d] = f2bf(vv);
                s[reg] += vv; sq[reg] += vv*vv;
            }
        }
        #pragma unroll
        for (int off=1; off<16; off<<=1)
            #pragma unroll
            for (int reg=0;reg<4;++reg){
                s[reg]  += __shfl_xor(s[reg],  off, 64);
                sq[reg] += __shfl_xor(sq[reg], off, 64);
            }
        if (m15 == 0){
            #pragma unroll
            for (int reg=0;reg<4;++reg){
                const int r = grow + 16*mt + q*4 + reg;
                atomicAdd(&stats[2*r],   s[reg]);
                atomicAdd(&stats[2*r+1], sq[reg]);
            }
        }
    }
}

// ---- GEMM2: out = x + rsig*(Tn_raw @ Wo'^T - mu*G) + B ----
__global__ __launch_bounds__(256) void kg2(
    const unsigned short* __restrict__ Tn, const unsigned short* __restrict__ Wb,
    const float* __restrict__ x, const float* __restrict__ stats,
    const float* __restrict__ Gv, const float* __restrict__ Bv,
    float* __restrict__ out)
{
    __shared__ short As[64*64], Bs[64*64];
    const int tid = threadIdx.x;
    const int row0 = blockIdx.x*64, n0 = blockIdx.y*64;
    floatx4 acc[2][2];
    #pragma unroll
    for (int mt=0;mt<2;++mt)
        #pragma unroll
        for (int nt=0;nt<2;++nt) acc[mt][nt] = (floatx4){0.f,0.f,0.f,0.f};
    gemm64x64(Tn + (size_t)row0*512, Wb + (size_t)(896+n0)*512, As, Bs, tid, acc);
    const int lane = tid & 63, w = tid >> 6;
    const int wm = w & 1, wn = w >> 1, q = lane >> 4, m15 = lane & 15;
    #pragma unroll
    for (int mt=0;mt<2;++mt)
        #pragma unroll
        for (int nt=0;nt<2;++nt){
            const int n = n0 + 32*wn + 16*nt + m15;
            const float Gn = Gv[n], Bn = Bv[n];
            #pragma unroll
            for (int reg=0;reg<4;++reg){
                const int m = row0 + 32*wm + 16*mt + q*4 + reg;
                const float2 st = ((const float2*)stats)[m];
                const float mu  = st.x*(1.f/512.f);
                const float var = st.y*(1.f/512.f) - mu*mu;
                const float rs  = rsqrtf(var + 1e-5f);
                out[(size_t)m*512 + n] = x[(size_t)m*512 + n]
                                       + rs*(acc[mt][nt][reg] - mu*Gn) + Bn;
            }
        }
}

extern "C" void kernel_launch(void* const* d_in, const int* in_sizes, int n_in,
                              void* d_out, int out_size, void* d_ws, size_t ws_size,
                              hipStream_t stream) {
    const float* x    = (const float*)d_in[0];
    const float* Wk   = (const float*)d_in[1];
    const float* bk   = (const float*)d_in[2];
    const float* Wq   = (const float*)d_in[3];
    const float* bq   = (const float*)d_in[4];
    const float* Wv   = (const float*)d_in[5];
    const float* bv   = (const float*)d_in[6];
    const float* ln_g = (const float*)d_in[7];
    const float* ln_b = (const float*)d_in[8];
    const float* Wo   = (const float*)d_in[9];
    const float* bo   = (const float*)d_in[10];
    const float* set_w      = (const float*)d_in[11];
    const float* pos_phases = (const float*)d_in[12];
    const float* pos_weight = (const float*)d_in[13];
    const float* Wg1  = (const float*)d_in[14];
    const float* bg1  = (const float*)d_in[15];
    const float* Wg2  = (const float*)d_in[16];
    const float* bg2  = (const float*)d_in[17];
    float* out = (float*)d_out;

    // workspace: fp32 region then bf16 region (~21.5 MB)
    float* ws    = (float*)d_ws;
    float* bcat  = ws;                                    // 1408 f32
    float* stats = bcat  + NW;                            // 2048*2 f32
    float* Gv    = stats + 4096;                          // 512 f32
    float* Bv    = Gv    + 512;                           // 512 f32
    float* P     = Bv    + 512;                           // 2*32*512*64 f32
    unsigned short* Wb  = (unsigned short*)(P + (size_t)BB*NCHUNK*512*NCH);
    unsigned short* xb  = Wb  + (size_t)NW*512;           // 2048*512
    unsigned short* Vt  = xb  + (size_t)2048*512;         // 2*512*1024
    unsigned short* ab  = Vt  + (size_t)BB*512*1024;      // 2048*64
    unsigned short* Rb  = ab  + (size_t)2048*NCH;         // 2048*64
    unsigned short* aT  = Rb  + (size_t)2048*NCH;         // 2*64*1024
    unsigned short* S0t = aT  + (size_t)BB*NCH*1024;      // 2*32*512*64
    unsigned short* Tn  = S0t + (size_t)BB*NCHUNK*512*NCH;// 2048*512

    k_prep<<<dim3(NW + 2048), 128, 0, stream>>>(
        Wv,Wg1,Wk,Wq,Wo, bv,bg1,bk,bq,bo, x, ln_g, ln_b,
        Wb, bcat, Gv, Bv, stats, xb);
    kg1f<<<dim3(288), 256, 0, stream>>>(
        xb, Wb, bcat, Wg2, bg2, set_w, pos_phases, pos_weight, Vt, ab, Rb, aT);
    k2a_chunksum<<<dim3(NCHUNK, BB, 4), 256, 0, stream>>>(aT, Vt, P);
    k2b_prefix<<<dim3(512*NCH/256, BB), 256, 0, stream>>>(P, S0t);
    k2c_scan<<<dim3(NCHUNK, BB, 4), 256, 0, stream>>>(ab, Rb, Vt, S0t, Tn, stats);
    kg2<<<dim3(2048/64, 512/64), 256, 0, stream>>>(Tn, Wb, x, stats, Gv, Bv, out);
}